// Round 14
// baseline (316.220 us; speedup 1.0000x reference)
//
#include <hip/hip_runtime.h>

// Sizes (fixed by setup_inputs)
#define BB   16
#define D1   128
#define D2   256
#define NP   8192
#define NG   2048
#define DC   384     // d1+d2
#define DH   256
#define DO   128
#define NPTS (BB*NP) // 131072
#define KRANGE 4
#define KSLICE (NG/KRANGE)  // 512

typedef unsigned int u32;
typedef unsigned short u16;
typedef short v8s __attribute__((ext_vector_type(8)));
typedef float v4f __attribute__((ext_vector_type(4)));

struct AF { v8s v[2][4]; };  // one k-step of A fragments (by-value copies stay in regs)

__device__ __forceinline__ u16 f2bf(float f) {
  u32 u = __builtin_bit_cast(u32, f);
  return (u16)((u + 0x7FFFu + ((u >> 16) & 1u)) >> 16);  // RNE
}
__device__ __forceinline__ float bf2f(u32 lo16) {
  return __builtin_bit_cast(float, lo16 << 16);
}

// async global->LDS, 16B per lane. LDS dest: wave-uniform base + lane*16.
__device__ __forceinline__ void gload16(const void* g, void* s) {
  __builtin_amdgcn_global_load_lds((const __attribute__((address_space(1))) void*)g,
                                   (__attribute__((address_space(3))) void*)s, 16, 0, 0);
}

// ---------------- prep: W1/W2 -> bf16, pre-swizzled [ks][m][blk^(m&7)][8] ----------------
__global__ __launch_bounds__(256) void prepw_kernel(const float* __restrict__ W1,
                                                    const float* __restrict__ W2,
                                                    u16* __restrict__ W1s, u16* __restrict__ W2s) {
  int id = blockIdx.x * 256 + threadIdx.x;
  if (id < 12288) {  // 6 ksteps * 256 m * 8 blk
    int ks = id >> 11, rem = id & 2047, m = rem >> 3, blk = rem & 7;
    int k = ks * 64 + (blk ^ (m & 7)) * 8;
    const float* src = W1 + m * 384 + k;
    u32 a0 = (u32)f2bf(src[0]) | ((u32)f2bf(src[1]) << 16);
    u32 a1 = (u32)f2bf(src[2]) | ((u32)f2bf(src[3]) << 16);
    u32 a2 = (u32)f2bf(src[4]) | ((u32)f2bf(src[5]) << 16);
    u32 a3 = (u32)f2bf(src[6]) | ((u32)f2bf(src[7]) << 16);
    uint4 v; v.x=a0; v.y=a1; v.z=a2; v.w=a3;
    *(uint4*)((char*)W1s + (long)id * 16) = v;
  }
  int id2 = id - 12288;
  if (id2 >= 0 && id2 < 4096) {  // 4 ksteps * 128 m * 8 blk
    int ks = id2 >> 10, rem = id2 & 1023, m = rem >> 3, blk = rem & 7;
    int k = ks * 64 + (blk ^ (m & 7)) * 8;
    const float* src = W2 + m * 256 + k;
    u32 a0 = (u32)f2bf(src[0]) | ((u32)f2bf(src[1]) << 16);
    u32 a1 = (u32)f2bf(src[2]) | ((u32)f2bf(src[3]) << 16);
    u32 a2 = (u32)f2bf(src[4]) | ((u32)f2bf(src[5]) << 16);
    u32 a3 = (u32)f2bf(src[6]) | ((u32)f2bf(src[7]) << 16);
    uint4 v; v.x=a0; v.y=a1; v.z=a2; v.w=a3;
    *(uint4*)((char*)W2s + (long)id2 * 16) = v;
  }
}

// ---------------- transpose feature2 [B][256][2048] f32 -> f2t [B][2048][256] bf16 ----------------
__global__ __launch_bounds__(256) void tf2_kernel(const float* __restrict__ f2, u16* __restrict__ f2t) {
  __shared__ float tl[64 * 65];
  int b = blockIdx.z, t = threadIdx.x;
  int c0 = blockIdx.y * 64, g0 = blockIdx.x * 64;
  const float* src = f2 + ((long)b * 256 + c0) * 2048 + g0;
  for (int i = t; i < 4096; i += 256) {
    int c = i >> 6, g = i & 63;
    tl[c * 65 + g] = src[(long)c * 2048 + g];
  }
  __syncthreads();
  for (int i = t; i < 2048; i += 256) {
    int g = i >> 5, cp = i & 31;
    int c = cp * 2;
    u32 v = (u32)f2bf(tl[c * 65 + g]) | ((u32)f2bf(tl[(c + 1) * 65 + g]) << 16);
    *(u32*)((char*)f2t + (((long)b * 2048 + g0 + g) * 256 + c0 + c) * 2) = v;
  }
}

// ---------------- knn part: FMA-approx mask (conservative superset), exact verbatim insert ----
// Mask gate uses contracted arithmetic + 1e-3 slack: |d_fma - d_exact| <= ~6e-5 (4 ulp @ |x|<=150),
// so {d_fma < t2v + 1e-3} is a strict superset of {d_exact < t2v}. The while-body recomputes d with
// the verbatim exact __f*_rn chain and re-checks dd < t0/t1/t2 before ANY state change (branchless
// update is a no-op otherwise, r6-verified) => selection & tie-breaks bit-identical.
__global__ __launch_bounds__(256) void knn_part_kernel(const float* __restrict__ c1, const float* __restrict__ c2,
                                                       float* __restrict__ ktD, int* __restrict__ ktI, int rbase) {
  __shared__ float4 sg[KSLICE];  // (x, y, z, |g|^2)
  int b = blockIdx.z, r = rbase + blockIdx.y, t = threadIdx.x;
  int base = r * KSLICE;
  const float* c2b = c2 + (long)b * 3 * NG;
  for (int g = t; g < KSLICE; g += 256) {
    int gg = base + g;
    float x = c2b[gg], y = c2b[NG + gg], z = c2b[2 * NG + gg];
    float s2 = __fadd_rn(__fadd_rn(__fmul_rn(x, x), __fmul_rn(y, y)), __fmul_rn(z, z));
    sg[g] = make_float4(x, y, z, s2);
  }
  __syncthreads();
  int p = blockIdx.x * 256 + t;
  const float* c1b = c1 + (long)b * 3 * NP;
  float px = c1b[p], py = c1b[NP + p], pz = c1b[2 * NP + p];
  float s1 = __fadd_rn(__fadd_rn(__fmul_rn(px, px), __fmul_rn(py, py)), __fmul_rn(pz, pz));
  float t0 = 1e30f, t1 = 1e30f, t2v = 1e30f;
  int i0 = 0, i1 = 0, i2 = 0;
  for (int g0 = 0; g0 < KSLICE; g0 += 8) {
    u32 mask = 0;
    float thr = t2v + 1e-3f;   // conservative gate (t2v=1e30 start: +1e-3 harmless)
    #pragma unroll
    for (int u = 0; u < 8; u++) {
      float4 q = sg[g0 + u];
      // contracted (FMA) approximation — gate only
      float dot = px * q.x + py * q.y + pz * q.z;
      float du = s1 + q.w - 2.0f * dot;
      mask |= (du < thr) ? (1u << u) : 0u;
    }
    while (mask) {
      int u = __builtin_ctz(mask);
      mask &= mask - 1;
      float4 q = sg[g0 + u];
      // exact verbatim distance for the actual update
      float dot = __fadd_rn(__fadd_rn(__fmul_rn(px, q.x), __fmul_rn(py, q.y)), __fmul_rn(pz, q.z));
      float dd = __fsub_rn(__fadd_rn(s1, q.w), __fmul_rn(2.0f, dot));
      int gi = base + g0 + u;
      bool c0 = dd < t0, cc1 = dd < t1, cc2 = dd < t2v;
      int ni2 = cc1 ? i1 : (cc2 ? gi : i2);
      int ni1 = c0 ? i0 : (cc1 ? gi : i1);
      int ni0 = c0 ? gi : i0;
      float nt2 = __builtin_amdgcn_fmed3f(t1, dd, t2v);
      float nt1 = __builtin_amdgcn_fmed3f(t0, dd, t1);
      float nt0 = fminf(t0, dd);
      t0 = nt0; t1 = nt1; t2v = nt2;
      i0 = ni0; i1 = ni1; i2 = ni2;
    }
  }
  long n = (long)b * NP + p;
  long o = (long)(r * 3) * NPTS + n;
  ktD[o] = t0; ktD[o + NPTS] = t1; ktD[o + 2 * (long)NPTS] = t2v;
  ktI[o] = i0; ktI[o + NPTS] = i1; ktI[o + 2 * (long)NPTS] = i2;
}

// ---------------- interp + fused knn-merge + concat -> feat rows (swizzled bf16) ----------------
__global__ __launch_bounds__(256) void interp_kernel(const float* __restrict__ f1, const u16* __restrict__ f2t,
                                                     const float* __restrict__ ktD, const int* __restrict__ ktI,
                                                     u16* __restrict__ feat) {
  __shared__ float tile[32 * 129];  // [p][c], stride 129 -> 2-way (free) read banks
  int b = blockIdx.y, t = threadIdx.x;
  long p0 = (long)blockIdx.x * 32;
  const float* f1b = f1 + (long)b * D1 * NP;
  #pragma unroll
  for (int k = 0; k < 16; k++) {
    int i = k * 256 + t;
    int c = i >> 5, p = i & 31;
    tile[p * 129 + c] = f1b[(long)c * NP + p0 + p];
  }
  __syncthreads();
  int p = t >> 3, q = t & 7;
  long n = (long)b * NP + p0 + p;
  char* row = (char*)feat + n * 768;
  int sw = p & 7;  // (n&7) == (p&7) since p0 % 32 == 0
  // f1 channels: c = g*64 + q*8 + j  (g=0..1, j=0..7)
  #pragma unroll
  for (int g = 0; g < 2; g++) {
    int c = g * 64 + q * 8;
    const float* tp = tile + p * 129 + c;
    u32 w0 = (u32)f2bf(tp[0]) | ((u32)f2bf(tp[1]) << 16);
    u32 w1 = (u32)f2bf(tp[2]) | ((u32)f2bf(tp[3]) << 16);
    u32 w2 = (u32)f2bf(tp[4]) | ((u32)f2bf(tp[5]) << 16);
    u32 w3 = (u32)f2bf(tp[6]) | ((u32)f2bf(tp[7]) << 16);
    uint4 v; v.x=w0; v.y=w1; v.z=w2; v.w=w3;
    *(uint4*)(row + g * 128 + ((q ^ sw) << 4)) = v;  // c6=g, kblk=q
  }
  // fused merge (verbatim knn_merge logic, redundant across the 8 q-threads)
  float t0 = 1e30f, t1 = 1e30f, t2v = 1e30f;
  int i0 = 0, i1 = 0, i2 = 0;
  #pragma unroll
  for (int e = 0; e < KRANGE * 3; e++) {
    float d = ktD[(long)e * NPTS + n];
    int gi = ktI[(long)e * NPTS + n];
    if (d < t2v) {
      if (d < t1) {
        t2v = t1; i2 = i1;
        if (d < t0) { t1 = t0; i1 = i0; t0 = d; i0 = gi; }
        else        { t1 = d;  i1 = gi; }
      } else { t2v = d; i2 = gi; }
    }
  }
  float rr0 = __fdiv_rn(1.0f, __fadd_rn(t0, 1e-8f));
  float rr1 = __fdiv_rn(1.0f, __fadd_rn(t1, 1e-8f));
  float rr2 = __fdiv_rn(1.0f, __fadd_rn(t2v, 1e-8f));
  float rs = __fadd_rn(__fadd_rn(rr0, rr1), rr2);
  float w0 = __fdiv_rn(rr0, rs);
  float w1 = __fdiv_rn(rr1, rs);
  float w2 = __fdiv_rn(rr2, rs);
  // interp channels: ci = g*64 + q*8 + j  (g=0..3, j=0..7), c = 128 + ci
  const char* fb = (const char*)f2t + (long)b * NG * 512;
  const char* r0 = fb + (long)i0 * 512;
  const char* r1 = fb + (long)i1 * 512;
  const char* r2 = fb + (long)i2 * 512;
  #pragma unroll
  for (int g = 0; g < 4; g++) {
    int ci = g * 64 + q * 8;
    uint4 a0 = *(const uint4*)(r0 + ci * 2);
    uint4 a1 = *(const uint4*)(r1 + ci * 2);
    uint4 a2 = *(const uint4*)(r2 + ci * 2);
    const u32* pa0 = (const u32*)&a0;
    const u32* pa1 = (const u32*)&a1;
    const u32* pa2 = (const u32*)&a2;
    u32 outw[4];
    #pragma unroll
    for (int h = 0; h < 4; h++) {
      u32 x0 = pa0[h], x1 = pa1[h], x2 = pa2[h];
      float lo = w0 * bf2f(x0 & 0xffff) + w1 * bf2f(x1 & 0xffff) + w2 * bf2f(x2 & 0xffff);
      float hi = w0 * bf2f(x0 >> 16)    + w1 * bf2f(x1 >> 16)    + w2 * bf2f(x2 >> 16);
      outw[h] = (u32)f2bf(lo) | ((u32)f2bf(hi) << 16);
    }
    uint4 v; v.x=outw[0]; v.y=outw[1]; v.z=outw[2]; v.w=outw[3];
    *(uint4*)(row + (2 + g) * 128 + ((q ^ sw) << 4)) = v;  // c6=2+g, kblk=q
  }
}

// ---------------- GEMM1: B double-buffered LDS (gload16), A register-prefetched from global ----
__global__ __launch_bounds__(256) void gemm1_kernel(const u16* __restrict__ W1s, const u16* __restrict__ feat,
                                                    const float* __restrict__ b1, u16* __restrict__ y1,
                                                    float* __restrict__ ps, float* __restrict__ pq) {
  __shared__ __attribute__((aligned(16))) char lds[32768];
  const int t = threadIdx.x, w = t >> 6, l = t & 63;
  const int wm = w >> 1, wn = w & 1;
  const int nb = blockIdx.y, mb = blockIdx.x;
  const long n0 = (long)nb * 128;
  const int m0 = mb * 128;
  const int lm = l & 15, lk = l >> 4, l7 = l & 7;
  v4f acc[4][4];
  #pragma unroll
  for (int i = 0; i < 4; i++)
    #pragma unroll
    for (int j = 0; j < 4; j++) { v4f z = {0.f,0.f,0.f,0.f}; acc[i][j] = z; }

  const char* aBase = (const char*)W1s + (long)(m0 + wm * 64 + lm) * 128;
  auto loadA = [&](int ks) {
    AF r;
    #pragma unroll
    for (int w32 = 0; w32 < 2; w32++) {
      int off = ((w32 * 4 + lk) ^ l7) << 4;
      #pragma unroll
      for (int mf = 0; mf < 4; mf++)
        r.v[w32][mf] = *(const v8s*)(aBase + mf * 2048 + ks * 32768 + off);
    }
    return r;
  };
  auto stageB = [&](int ks, int buf) {
    char* dstB = (char*)lds + buf * 16384 + w * 4096;
    #pragma unroll
    for (int i = 0; i < 4; i++) {
      int a = w * 4096 + i * 1024 + l * 16;
      int n = a >> 7, r = a & 127;
      gload16((const char*)feat + (n0 + n) * 768 + ks * 128 + r, dstB + i * 1024);
    }
  };

  AF aCur = loadA(0);
  stageB(0, 0);
  __syncthreads();
  #pragma unroll
  for (int ks = 0; ks < 6; ks++) {
    const int buf = ks & 1;
    AF aNxt;
    if (ks < 5) { stageB(ks + 1, buf ^ 1); aNxt = loadA(ks + 1); }
    const char* Bp = (const char*)lds + buf * 16384;
    #pragma unroll
    for (int w32 = 0; w32 < 2; w32++) {
      int off = ((w32 * 4 + lk) ^ l7) << 4;
      v8s bfr[4];
      #pragma unroll
      for (int nf = 0; nf < 4; nf++)
        bfr[nf] = *(const v8s*)(Bp + (wn * 64 + nf * 16 + lm) * 128 + off);
      #pragma unroll
      for (int mf = 0; mf < 4; mf++)
        #pragma unroll
        for (int nf = 0; nf < 4; nf++)
          acc[mf][nf] = __builtin_amdgcn_mfma_f32_16x16x32_bf16(aCur.v[w32][mf], bfr[nf], acc[mf][nf], 0, 0, 0);
    }
    __syncthreads();
    if (ks < 5) aCur = aNxt;
  }

  #pragma unroll
  for (int mf = 0; mf < 4; mf++) {
    int m = m0 + wm * 64 + mf * 16 + lk * 4;
    float bb0 = b1[m], bb1 = b1[m+1], bb2 = b1[m+2], bb3 = b1[m+3];
    #pragma unroll
    for (int nf = 0; nf < 4; nf++) {
      long n = n0 + wn * 64 + nf * 16 + lm;
      v4f v = acc[mf][nf];
      v[0] += bb0; v[1] += bb1; v[2] += bb2; v[3] += bb3;
      acc[mf][nf] = v;
      uint2 pk;
      pk.x = (u32)f2bf(v[0]) | ((u32)f2bf(v[1]) << 16);
      pk.y = (u32)f2bf(v[2]) | ((u32)f2bf(v[3]) << 16);
      *(uint2*)((char*)y1 + (n * 256 + m) * 2) = pk;
    }
  }
  #pragma unroll
  for (int mf = 0; mf < 4; mf++) {
    #pragma unroll
    for (int j = 0; j < 4; j++) {
      float s = 0.f, q = 0.f;
      #pragma unroll
      for (int nf = 0; nf < 4; nf++) { float v = acc[mf][nf][j]; s += v; q += v * v; }
      #pragma unroll
      for (int mask = 1; mask <= 8; mask <<= 1) { s += __shfl_xor(s, mask); q += __shfl_xor(q, mask); }
      if (lm == 0) {
        int m = m0 + wm * 64 + mf * 16 + lk * 4 + j;
        int col = nb * 2 + wn;
        ps[(long)m * 2048 + col] = s;
        pq[(long)m * 2048 + col] = q;
      }
    }
  }
}

// ---------------- stats: per-channel mean/var -> scale/shift ----------------
__global__ __launch_bounds__(256) void stats_kernel(const float* __restrict__ ps, const float* __restrict__ pq,
                                                    const float* __restrict__ gamma, const float* __restrict__ beta,
                                                    float* __restrict__ scsh, int ncols, float invN) {
  int m = blockIdx.x, t = threadIdx.x;
  float s = 0.f, q = 0.f;
  for (int i = t; i < ncols; i += 256) { s += ps[(long)m * ncols + i]; q += pq[(long)m * ncols + i]; }
  __shared__ float rs[4], rq[4];
  #pragma unroll
  for (int mask = 1; mask <= 32; mask <<= 1) { s += __shfl_xor(s, mask); q += __shfl_xor(q, mask); }
  int w = t >> 6;
  if ((t & 63) == 0) { rs[w] = s; rq[w] = q; }
  __syncthreads();
  if (t == 0) {
    s = rs[0] + rs[1] + rs[2] + rs[3];
    q = rq[0] + rq[1] + rq[2] + rq[3];
    float mean = s * invN;
    float var = q * invN - mean * mean;
    float rstd = rsqrtf(var + 1e-5f);
    float sc = gamma[m] * rstd;
    scsh[m] = sc;
    scsh[gridDim.x + m] = beta[m] - mean * sc;
  }
}

// ---------------- GEMM2: B (BN1+ReLU) double-buffered LDS, A register-prefetched from global ----
__global__ __launch_bounds__(256) void gemm2_kernel(const u16* __restrict__ W2s, const u16* __restrict__ y1,
                                                    const float* __restrict__ scsh, const float* __restrict__ b2,
                                                    u16* __restrict__ y2, float* __restrict__ ps, float* __restrict__ pq) {
  __shared__ __attribute__((aligned(16))) char lds[32768];
  const int t = threadIdx.x, w = t >> 6, l = t & 63;
  const int wm = w >> 1, wn = w & 1;
  const int nb = blockIdx.x;
  const long n0 = (long)nb * 128;
  const int lm = l & 15, lk = l >> 4, l7 = l & 7;
  v4f acc[4][4];
  #pragma unroll
  for (int i = 0; i < 4; i++)
    #pragma unroll
    for (int j = 0; j < 4; j++) { v4f z = {0.f,0.f,0.f,0.f}; acc[i][j] = z; }
  uint4 breg[4];

  const char* aBase = (const char*)W2s + (long)(wm * 64 + lm) * 128;
  auto loadA = [&](int ks) {
    AF r;
    #pragma unroll
    for (int w32 = 0; w32 < 2; w32++) {
      int off = ((w32 * 4 + lk) ^ l7) << 4;
      #pragma unroll
      for (int mf = 0; mf < 4; mf++)
        r.v[w32][mf] = *(const v8s*)(aBase + mf * 2048 + ks * 16384 + off);
    }
    return r;
  };
  auto loadB = [&](int ks) {
    #pragma unroll
    for (int i = 0; i < 4; i++) {
      int idx = i * 256 + t, n = idx >> 3, blk = idx & 7;
      breg[i] = *(const uint4*)((const char*)y1 + (n0 + n) * 512 + ks * 128 + blk * 16);
    }
  };
  auto writeB = [&](int ks, int buf) {
    #pragma unroll
    for (int i = 0; i < 4; i++) {
      int idx = i * 256 + t, n = idx >> 3, blk = idx & 7;
      const u32* pr = (const u32*)&breg[i];
      u32 outw[4];
      #pragma unroll
      for (int h = 0; h < 4; h++) {
        int k = ks * 64 + blk * 8 + 2 * h;
        u32 x = pr[h];
        float h0 = fmaxf(0.f, scsh[k]     * bf2f(x & 0xffff) + scsh[256 + k]);
        float h1 = fmaxf(0.f, scsh[k + 1] * bf2f(x >> 16)    + scsh[256 + k + 1]);
        outw[h] = (u32)f2bf(h0) | ((u32)f2bf(h1) << 16);
      }
      uint4 v; v.x=outw[0]; v.y=outw[1]; v.z=outw[2]; v.w=outw[3];
      *(uint4*)((char*)lds + buf * 16384 + n * 128 + ((blk ^ (n & 7)) << 4)) = v;
    }
  };

  loadB(0); writeB(0, 0);
  AF aCur = loadA(0);
  __syncthreads();
  #pragma unroll
  for (int ks = 0; ks < 4; ks++) {
    const int buf = ks & 1;
    AF aNxt;
    if (ks < 3) { loadB(ks + 1); aNxt = loadA(ks + 1); }
    const char* Bp = (const char*)lds + buf * 16384;
    #pragma unroll
    for (int w32 = 0; w32 < 2; w32++) {
      int off = ((w32 * 4 + lk) ^ l7) << 4;
      v8s bfr[4];
      #pragma unroll
      for (int nf = 0; nf < 4; nf++)
        bfr[nf] = *(const v8s*)(Bp + (wn * 64 + nf * 16 + lm) * 128 + off);
      #pragma unroll
      for (int mf = 0; mf < 4; mf++)
        #pragma unroll
        for (int nf = 0; nf < 4; nf++)
          acc[mf][nf] = __builtin_amdgcn_mfma_f32_16x16x32_bf16(aCur.v[w32][mf], bfr[nf], acc[mf][nf], 0, 0, 0);
    }
    if (ks < 3) writeB(ks + 1, buf ^ 1);
    __syncthreads();
    if (ks < 3) aCur = aNxt;
  }

  #pragma unroll
  for (int mf = 0; mf < 4; mf++) {
    int m = wm * 64 + mf * 16 + lk * 4;
    float bb0 = b2[m], bb1 = b2[m+1], bb2v = b2[m+2], bb3 = b2[m+3];
    #pragma unroll
    for (int nf = 0; nf < 4; nf++) {
      long n = n0 + wn * 64 + nf * 16 + lm;
      v4f v = acc[mf][nf];
      v[0] += bb0; v[1] += bb1; v[2] += bb2v; v[3] += bb3;
      acc[mf][nf] = v;
      uint2 pk;
      pk.x = (u32)f2bf(v[0]) | ((u32)f2bf(v[1]) << 16);
      pk.y = (u32)f2bf(v[2]) | ((u32)f2bf(v[3]) << 16);
      *(uint2*)((char*)y2 + (n * 128 + m) * 2) = pk;
    }
  }
  #pragma unroll
  for (int mf = 0; mf < 4; mf++) {
    #pragma unroll
    for (int j = 0; j < 4; j++) {
      float s = 0.f, q = 0.f;
      #pragma unroll
      for (int nf = 0; nf < 4; nf++) { float v = acc[mf][nf][j]; s += v; q += v * v; }
      #pragma unroll
      for (int mask = 1; mask <= 8; mask <<= 1) { s += __shfl_xor(s, mask); q += __shfl_xor(q, mask); }
      if (lm == 0) {
        int m = wm * 64 + mf * 16 + lk * 4 + j;
        int col = nb * 2 + wn;
        ps[(long)m * 2048 + col] = s;
        pq[(long)m * 2048 + col] = q;
      }
    }
  }
}

// ---------------- final: out[b][m][p] = relu(bn2(y2)), transpose via LDS ----------------
__global__ __launch_bounds__(256) void final_kernel(const u16* __restrict__ y2, const float* __restrict__ scsh2,
                                                    float* __restrict__ out) {
  __shared__ float tl[64 * 130];
  __shared__ float sc[128], sh[128];
  int b = blockIdx.y, t = threadIdx.x;
  long p0 = (long)blockIdx.x * 64;
  if (t < 128) { sc[t] = scsh2[t]; sh[t] = scsh2[128 + t]; }
  __syncthreads();
  #pragma unroll
  for (int i = 0; i < 4; i++) {
    int idx = i * 256 + t;
    int n = idx >> 4, cb = idx & 15;
    uint4 v = *(const uint4*)((const char*)y2 + (((long)b * NP + p0 + n) * 128 + cb * 8) * 2);
    const u32* pv = (const u32*)&v;
    #pragma unroll
    for (int h = 0; h < 4; h++) {
      int m = cb * 8 + 2 * h;
      u32 x = pv[h];
      tl[n * 130 + m]     = fmaxf(0.f, sc[m]     * bf2f(x & 0xffff) + sh[m]);
      tl[n * 130 + m + 1] = fmaxf(0.f, sc[m + 1] * bf2f(x >> 16)    + sh[m + 1]);
    }
  }
  __syncthreads();
  int m = t & 127, hh = t >> 7;
  float* dst = out + ((long)b * 128 + m) * NP + p0 + hh * 32;
  #pragma unroll
  for (int j = 0; j < 8; j++) {
    int p = hh * 32 + j * 4;
    float4 v;
    v.x = tl[(p + 0) * 130 + m];
    v.y = tl[(p + 1) * 130 + m];
    v.z = tl[(p + 2) * 130 + m];
    v.w = tl[(p + 3) * 130 + m];
    *(float4*)(dst + j * 4) = v;
  }
}

extern "C" void kernel_launch(void* const* d_in, const int* in_sizes, int n_in,
                              void* d_out, int out_size, void* d_ws, size_t ws_size,
                              hipStream_t stream) {
  const float* f1  = (const float*)d_in[0];
  const float* c1  = (const float*)d_in[1];
  const float* f2  = (const float*)d_in[2];
  const float* c2  = (const float*)d_in[3];
  const float* W1  = (const float*)d_in[4];
  const float* b1  = (const float*)d_in[5];
  const float* g1  = (const float*)d_in[6];
  const float* be1 = (const float*)d_in[7];
  const float* W2  = (const float*)d_in[8];
  const float* b2  = (const float*)d_in[9];
  const float* g2  = (const float*)d_in[10];
  const float* be2 = (const float*)d_in[11];
  float* out = (float*)d_out;

  char* ws = (char*)d_ws;
  size_t off = 0;
  auto alloc = [&](size_t sz) { char* p = ws + off; off = (off + sz + 255) & ~(size_t)255; return p; };
  u16*   f2t   = (u16*)  alloc((size_t)BB * NG * D2 * 2);       // 16.8 MB
  u16*   W1s   = (u16*)  alloc(196608);
  u16*   W2s   = (u16*)  alloc(65536);
  float* ps1   = (float*)alloc((size_t)256 * 2048 * 4);
  float* pq1   = (float*)alloc((size_t)256 * 2048 * 4);
  float* scsh1 = (float*)alloc(2048);
  float* ps2   = (float*)alloc((size_t)128 * 2048 * 4);
  float* pq2   = (float*)alloc((size_t)128 * 2048 * 4);
  float* scsh2 = (float*)alloc(1024);
  u16*   y1    = (u16*)  alloc((size_t)NPTS * DH * 2);          // 67 MB
  u16*   feat  = (u16*)  alloc((size_t)NPTS * DC * 2);          // 100 MB
  u16*   y2    = (u16*)  feat;  // alias: feat dead once GEMM2 starts

  // knn scratch aliases y1 (y1 only live from gemm1 onward; knn scratch dead by then)
  float* ktD = (float*)y1;                                      // 6.29 MB
  int*   ktI = (int*)((char*)y1 + (size_t)KRANGE * 3 * NPTS * 4 + 256); // 6.29 MB

  hipLaunchKernelGGL(prepw_kernel, dim3(64), dim3(256), 0, stream, W1, W2, W1s, W2s);
  hipLaunchKernelGGL(tf2_kernel, dim3(NG / 64, D2 / 64, BB), dim3(256), 0, stream, f2, f2t);
  hipLaunchKernelGGL(knn_part_kernel, dim3(NP / 256, 2, BB), dim3(256), 0, stream, c1, c2, ktD, ktI, 0);
  hipLaunchKernelGGL(knn_part_kernel, dim3(NP / 256, 2, BB), dim3(256), 0, stream, c1, c2, ktD, ktI, 2);
  hipLaunchKernelGGL(interp_kernel, dim3(NP / 32, BB), dim3(256), 0, stream, f1, f2t, ktD, ktI, feat);
  hipLaunchKernelGGL(gemm1_kernel, dim3(2, NPTS / 128), dim3(256), 0, stream, W1s, feat, b1, y1, ps1, pq1);
  hipLaunchKernelGGL(stats_kernel, dim3(256), dim3(256), 0, stream, ps1, pq1, g1, be1, scsh1, 2048, 1.f / (float)NPTS);
  hipLaunchKernelGGL(gemm2_kernel, dim3(NPTS / 128), dim3(256), 0, stream, W2s, y1, scsh1, b2, y2, ps2, pq2);
  hipLaunchKernelGGL(stats_kernel, dim3(128), dim3(256), 0, stream, ps2, pq2, g2, be2, scsh2, 2048, 1.f / (float)NPTS);
  hipLaunchKernelGGL(final_kernel, dim3(NP / 64, BB), dim3(256), 0, stream, y2, scsh2, out);
}

// Round 15
// 313.739 us; speedup vs baseline: 1.0079x; 1.0079x over previous
//
#include <hip/hip_runtime.h>

// Sizes (fixed by setup_inputs)
#define BB   16
#define D1   128
#define D2   256
#define NP   8192
#define NG   2048
#define DC   384     // d1+d2
#define DH   256
#define DO   128
#define NPTS (BB*NP) // 131072
#define KRANGE 4
#define KSLICE (NG/KRANGE)  // 512

typedef unsigned int u32;
typedef unsigned short u16;
typedef short v8s __attribute__((ext_vector_type(8)));
typedef float v4f __attribute__((ext_vector_type(4)));

struct AF { v8s v[2][4]; };  // one k-step of A fragments (by-value copies stay in regs)

__device__ __forceinline__ u16 f2bf(float f) {
  u32 u = __builtin_bit_cast(u32, f);
  return (u16)((u + 0x7FFFu + ((u >> 16) & 1u)) >> 16);  // RNE
}
__device__ __forceinline__ float bf2f(u32 lo16) {
  return __builtin_bit_cast(float, lo16 << 16);
}

// async global->LDS, 16B per lane. LDS dest: wave-uniform base + lane*16.
__device__ __forceinline__ void gload16(const void* g, void* s) {
  __builtin_amdgcn_global_load_lds((const __attribute__((address_space(1))) void*)g,
                                   (__attribute__((address_space(3))) void*)s, 16, 0, 0);
}

// ---------------- prep: W1/W2 -> bf16, pre-swizzled [ks][m][blk^(m&7)][8] ----------------
__global__ __launch_bounds__(256) void prepw_kernel(const float* __restrict__ W1,
                                                    const float* __restrict__ W2,
                                                    u16* __restrict__ W1s, u16* __restrict__ W2s) {
  int id = blockIdx.x * 256 + threadIdx.x;
  if (id < 12288) {  // 6 ksteps * 256 m * 8 blk
    int ks = id >> 11, rem = id & 2047, m = rem >> 3, blk = rem & 7;
    int k = ks * 64 + (blk ^ (m & 7)) * 8;
    const float* src = W1 + m * 384 + k;
    u32 a0 = (u32)f2bf(src[0]) | ((u32)f2bf(src[1]) << 16);
    u32 a1 = (u32)f2bf(src[2]) | ((u32)f2bf(src[3]) << 16);
    u32 a2 = (u32)f2bf(src[4]) | ((u32)f2bf(src[5]) << 16);
    u32 a3 = (u32)f2bf(src[6]) | ((u32)f2bf(src[7]) << 16);
    uint4 v; v.x=a0; v.y=a1; v.z=a2; v.w=a3;
    *(uint4*)((char*)W1s + (long)id * 16) = v;
  }
  int id2 = id - 12288;
  if (id2 >= 0 && id2 < 4096) {  // 4 ksteps * 128 m * 8 blk
    int ks = id2 >> 10, rem = id2 & 1023, m = rem >> 3, blk = rem & 7;
    int k = ks * 64 + (blk ^ (m & 7)) * 8;
    const float* src = W2 + m * 256 + k;
    u32 a0 = (u32)f2bf(src[0]) | ((u32)f2bf(src[1]) << 16);
    u32 a1 = (u32)f2bf(src[2]) | ((u32)f2bf(src[3]) << 16);
    u32 a2 = (u32)f2bf(src[4]) | ((u32)f2bf(src[5]) << 16);
    u32 a3 = (u32)f2bf(src[6]) | ((u32)f2bf(src[7]) << 16);
    uint4 v; v.x=a0; v.y=a1; v.z=a2; v.w=a3;
    *(uint4*)((char*)W2s + (long)id2 * 16) = v;
  }
}

// ---------------- transpose feature2 [B][256][2048] f32 -> f2t [B][2048][256] bf16 ----------------
__global__ __launch_bounds__(256) void tf2_kernel(const float* __restrict__ f2, u16* __restrict__ f2t) {
  __shared__ float tl[64 * 65];
  int b = blockIdx.z, t = threadIdx.x;
  int c0 = blockIdx.y * 64, g0 = blockIdx.x * 64;
  const float* src = f2 + ((long)b * 256 + c0) * 2048 + g0;
  for (int i = t; i < 4096; i += 256) {
    int c = i >> 6, g = i & 63;
    tl[c * 65 + g] = src[(long)c * 2048 + g];
  }
  __syncthreads();
  for (int i = t; i < 2048; i += 256) {
    int g = i >> 5, cp = i & 31;
    int c = cp * 2;
    u32 v = (u32)f2bf(tl[c * 65 + g]) | ((u32)f2bf(tl[(c + 1) * 65 + g]) << 16);
    *(u32*)((char*)f2t + (((long)b * 2048 + g0 + g) * 256 + c0 + c) * 2) = v;
  }
}

// ---------------- knn part: FMA-approx mask (conservative superset), exact verbatim insert ----
__global__ __launch_bounds__(256) void knn_part_kernel(const float* __restrict__ c1, const float* __restrict__ c2,
                                                       float* __restrict__ ktD, int* __restrict__ ktI, int rbase) {
  __shared__ float4 sg[KSLICE];  // (x, y, z, |g|^2)
  int b = blockIdx.z, r = rbase + blockIdx.y, t = threadIdx.x;
  int base = r * KSLICE;
  const float* c2b = c2 + (long)b * 3 * NG;
  for (int g = t; g < KSLICE; g += 256) {
    int gg = base + g;
    float x = c2b[gg], y = c2b[NG + gg], z = c2b[2 * NG + gg];
    float s2 = __fadd_rn(__fadd_rn(__fmul_rn(x, x), __fmul_rn(y, y)), __fmul_rn(z, z));
    sg[g] = make_float4(x, y, z, s2);
  }
  __syncthreads();
  int p = blockIdx.x * 256 + t;
  const float* c1b = c1 + (long)b * 3 * NP;
  float px = c1b[p], py = c1b[NP + p], pz = c1b[2 * NP + p];
  float s1 = __fadd_rn(__fadd_rn(__fmul_rn(px, px), __fmul_rn(py, py)), __fmul_rn(pz, pz));
  float t0 = 1e30f, t1 = 1e30f, t2v = 1e30f;
  int i0 = 0, i1 = 0, i2 = 0;
  for (int g0 = 0; g0 < KSLICE; g0 += 8) {
    u32 mask = 0;
    float thr = t2v + 1e-3f;   // conservative gate (t2v=1e30 start: +1e-3 harmless)
    #pragma unroll
    for (int u = 0; u < 8; u++) {
      float4 q = sg[g0 + u];
      float dot = px * q.x + py * q.y + pz * q.z;   // contracted approx — gate only
      float du = s1 + q.w - 2.0f * dot;
      mask |= (du < thr) ? (1u << u) : 0u;
    }
    while (mask) {
      int u = __builtin_ctz(mask);
      mask &= mask - 1;
      float4 q = sg[g0 + u];
      float dot = __fadd_rn(__fadd_rn(__fmul_rn(px, q.x), __fmul_rn(py, q.y)), __fmul_rn(pz, q.z));
      float dd = __fsub_rn(__fadd_rn(s1, q.w), __fmul_rn(2.0f, dot));
      int gi = base + g0 + u;
      bool c0 = dd < t0, cc1 = dd < t1, cc2 = dd < t2v;
      int ni2 = cc1 ? i1 : (cc2 ? gi : i2);
      int ni1 = c0 ? i0 : (cc1 ? gi : i1);
      int ni0 = c0 ? gi : i0;
      float nt2 = __builtin_amdgcn_fmed3f(t1, dd, t2v);
      float nt1 = __builtin_amdgcn_fmed3f(t0, dd, t1);
      float nt0 = fminf(t0, dd);
      t0 = nt0; t1 = nt1; t2v = nt2;
      i0 = ni0; i1 = ni1; i2 = ni2;
    }
  }
  long n = (long)b * NP + p;
  long o = (long)(r * 3) * NPTS + n;
  ktD[o] = t0; ktD[o + NPTS] = t1; ktD[o + 2 * (long)NPTS] = t2v;
  ktI[o] = i0; ktI[o + NPTS] = i1; ktI[o + 2 * (long)NPTS] = i2;
}

// ---------------- interp + fused knn-merge + concat -> feat rows (swizzled bf16) ----------------
__global__ __launch_bounds__(256) void interp_kernel(const float* __restrict__ f1, const u16* __restrict__ f2t,
                                                     const float* __restrict__ ktD, const int* __restrict__ ktI,
                                                     u16* __restrict__ feat) {
  __shared__ float tile[32 * 129];  // [p][c], stride 129 -> 2-way (free) read banks
  int b = blockIdx.y, t = threadIdx.x;
  long p0 = (long)blockIdx.x * 32;
  const float* f1b = f1 + (long)b * D1 * NP;
  #pragma unroll
  for (int k = 0; k < 16; k++) {
    int i = k * 256 + t;
    int c = i >> 5, p = i & 31;
    tile[p * 129 + c] = f1b[(long)c * NP + p0 + p];
  }
  __syncthreads();
  int p = t >> 3, q = t & 7;
  long n = (long)b * NP + p0 + p;
  char* row = (char*)feat + n * 768;
  int sw = p & 7;  // (n&7) == (p&7) since p0 % 32 == 0
  // f1 channels: c = g*64 + q*8 + j  (g=0..1, j=0..7)
  #pragma unroll
  for (int g = 0; g < 2; g++) {
    int c = g * 64 + q * 8;
    const float* tp = tile + p * 129 + c;
    u32 w0 = (u32)f2bf(tp[0]) | ((u32)f2bf(tp[1]) << 16);
    u32 w1 = (u32)f2bf(tp[2]) | ((u32)f2bf(tp[3]) << 16);
    u32 w2 = (u32)f2bf(tp[4]) | ((u32)f2bf(tp[5]) << 16);
    u32 w3 = (u32)f2bf(tp[6]) | ((u32)f2bf(tp[7]) << 16);
    uint4 v; v.x=w0; v.y=w1; v.z=w2; v.w=w3;
    *(uint4*)(row + g * 128 + ((q ^ sw) << 4)) = v;  // c6=g, kblk=q
  }
  // fused merge (verbatim knn_merge logic, redundant across the 8 q-threads)
  float t0 = 1e30f, t1 = 1e30f, t2v = 1e30f;
  int i0 = 0, i1 = 0, i2 = 0;
  #pragma unroll
  for (int e = 0; e < KRANGE * 3; e++) {
    float d = ktD[(long)e * NPTS + n];
    int gi = ktI[(long)e * NPTS + n];
    if (d < t2v) {
      if (d < t1) {
        t2v = t1; i2 = i1;
        if (d < t0) { t1 = t0; i1 = i0; t0 = d; i0 = gi; }
        else        { t1 = d;  i1 = gi; }
      } else { t2v = d; i2 = gi; }
    }
  }
  float rr0 = __fdiv_rn(1.0f, __fadd_rn(t0, 1e-8f));
  float rr1 = __fdiv_rn(1.0f, __fadd_rn(t1, 1e-8f));
  float rr2 = __fdiv_rn(1.0f, __fadd_rn(t2v, 1e-8f));
  float rs = __fadd_rn(__fadd_rn(rr0, rr1), rr2);
  float w0 = __fdiv_rn(rr0, rs);
  float w1 = __fdiv_rn(rr1, rs);
  float w2 = __fdiv_rn(rr2, rs);
  // interp channels: ci = g*64 + q*8 + j  (g=0..3, j=0..7), c = 128 + ci
  const char* fb = (const char*)f2t + (long)b * NG * 512;
  const char* r0 = fb + (long)i0 * 512;
  const char* r1 = fb + (long)i1 * 512;
  const char* r2 = fb + (long)i2 * 512;
  #pragma unroll
  for (int g = 0; g < 4; g++) {
    int ci = g * 64 + q * 8;
    uint4 a0 = *(const uint4*)(r0 + ci * 2);
    uint4 a1 = *(const uint4*)(r1 + ci * 2);
    uint4 a2 = *(const uint4*)(r2 + ci * 2);
    const u32* pa0 = (const u32*)&a0;
    const u32* pa1 = (const u32*)&a1;
    const u32* pa2 = (const u32*)&a2;
    u32 outw[4];
    #pragma unroll
    for (int h = 0; h < 4; h++) {
      u32 x0 = pa0[h], x1 = pa1[h], x2 = pa2[h];
      float lo = w0 * bf2f(x0 & 0xffff) + w1 * bf2f(x1 & 0xffff) + w2 * bf2f(x2 & 0xffff);
      float hi = w0 * bf2f(x0 >> 16)    + w1 * bf2f(x1 >> 16)    + w2 * bf2f(x2 >> 16);
      outw[h] = (u32)f2bf(lo) | ((u32)f2bf(hi) << 16);
    }
    uint4 v; v.x=outw[0]; v.y=outw[1]; v.z=outw[2]; v.w=outw[3];
    *(uint4*)(row + (2 + g) * 128 + ((q ^ sw) << 4)) = v;  // c6=2+g, kblk=q
  }
}

// ---------------- GEMM1: 512 threads, 8 waves (2m x 4n), per-wave 64x32 output ----------------
// acc halves to 8 fragments (32 AGPR) -> ~4 waves/SIMD. B double-buffered LDS (gload16),
// A register-prefetched from L2-resident W1s. Fragment bytes identical to prior rounds.
__global__ __launch_bounds__(512, 4) void gemm1_kernel(const u16* __restrict__ W1s, const u16* __restrict__ feat,
                                                       const float* __restrict__ b1, u16* __restrict__ y1,
                                                       float* __restrict__ ps, float* __restrict__ pq) {
  __shared__ __attribute__((aligned(16))) char lds[32768];
  const int t = threadIdx.x, w = t >> 6, l = t & 63;
  const int wm = w >> 2, wn = w & 3;
  const int nb = blockIdx.y, mb = blockIdx.x;
  const long n0 = (long)nb * 128;
  const int m0 = mb * 128;
  const int lm = l & 15, lk = l >> 4, l7 = l & 7;
  v4f acc[4][2];
  #pragma unroll
  for (int i = 0; i < 4; i++)
    #pragma unroll
    for (int j = 0; j < 2; j++) { v4f z = {0.f,0.f,0.f,0.f}; acc[i][j] = z; }

  const char* aBase = (const char*)W1s + (long)(m0 + wm * 64 + lm) * 128;
  auto loadA = [&](int ks) {
    AF r;
    #pragma unroll
    for (int w32 = 0; w32 < 2; w32++) {
      int off = ((w32 * 4 + lk) ^ l7) << 4;
      #pragma unroll
      for (int mf = 0; mf < 4; mf++)
        r.v[w32][mf] = *(const v8s*)(aBase + mf * 2048 + ks * 32768 + off);
    }
    return r;
  };
  auto stageB = [&](int ks, int buf) {
    #pragma unroll
    for (int i = 0; i < 2; i++) {
      int a = i * 8192 + w * 1024 + l * 16;
      int n = a >> 7, r = a & 127;
      gload16((const char*)feat + (n0 + n) * 768 + ks * 128 + r,
              (char*)lds + buf * 16384 + i * 8192 + w * 1024);
    }
  };

  AF aCur = loadA(0);
  stageB(0, 0);
  __syncthreads();
  #pragma unroll
  for (int ks = 0; ks < 6; ks++) {
    const int buf = ks & 1;
    AF aNxt;
    if (ks < 5) { stageB(ks + 1, buf ^ 1); aNxt = loadA(ks + 1); }
    const char* Bp = (const char*)lds + buf * 16384;
    #pragma unroll
    for (int w32 = 0; w32 < 2; w32++) {
      int off = ((w32 * 4 + lk) ^ l7) << 4;
      v8s bfr[2];
      #pragma unroll
      for (int nf = 0; nf < 2; nf++)
        bfr[nf] = *(const v8s*)(Bp + (wn * 32 + nf * 16 + lm) * 128 + off);
      #pragma unroll
      for (int mf = 0; mf < 4; mf++)
        #pragma unroll
        for (int nf = 0; nf < 2; nf++)
          acc[mf][nf] = __builtin_amdgcn_mfma_f32_16x16x32_bf16(aCur.v[w32][mf], bfr[nf], acc[mf][nf], 0, 0, 0);
    }
    __syncthreads();
    if (ks < 5) aCur = aNxt;
  }

  #pragma unroll
  for (int mf = 0; mf < 4; mf++) {
    int m = m0 + wm * 64 + mf * 16 + lk * 4;
    float bb0 = b1[m], bb1 = b1[m+1], bb2 = b1[m+2], bb3 = b1[m+3];
    #pragma unroll
    for (int nf = 0; nf < 2; nf++) {
      long n = n0 + wn * 32 + nf * 16 + lm;
      v4f v = acc[mf][nf];
      v[0] += bb0; v[1] += bb1; v[2] += bb2; v[3] += bb3;
      acc[mf][nf] = v;
      uint2 pk;
      pk.x = (u32)f2bf(v[0]) | ((u32)f2bf(v[1]) << 16);
      pk.y = (u32)f2bf(v[2]) | ((u32)f2bf(v[3]) << 16);
      *(uint2*)((char*)y1 + (n * 256 + m) * 2) = pk;
    }
  }
  #pragma unroll
  for (int mf = 0; mf < 4; mf++) {
    #pragma unroll
    for (int j = 0; j < 4; j++) {
      float s = 0.f, q = 0.f;
      #pragma unroll
      for (int nf = 0; nf < 2; nf++) { float v = acc[mf][nf][j]; s += v; q += v * v; }
      #pragma unroll
      for (int mask = 1; mask <= 8; mask <<= 1) { s += __shfl_xor(s, mask); q += __shfl_xor(q, mask); }
      if (lm == 0) {
        int m = m0 + wm * 64 + mf * 16 + lk * 4 + j;
        int col = nb * 4 + wn;
        ps[(long)m * 4096 + col] = s;
        pq[(long)m * 4096 + col] = q;
      }
    }
  }
}

// ---------------- stats: per-channel mean/var -> scale/shift ----------------
__global__ __launch_bounds__(256) void stats_kernel(const float* __restrict__ ps, const float* __restrict__ pq,
                                                    const float* __restrict__ gamma, const float* __restrict__ beta,
                                                    float* __restrict__ scsh, int ncols, float invN) {
  int m = blockIdx.x, t = threadIdx.x;
  float s = 0.f, q = 0.f;
  for (int i = t; i < ncols; i += 256) { s += ps[(long)m * ncols + i]; q += pq[(long)m * ncols + i]; }
  __shared__ float rs[4], rq[4];
  #pragma unroll
  for (int mask = 1; mask <= 32; mask <<= 1) { s += __shfl_xor(s, mask); q += __shfl_xor(q, mask); }
  int w = t >> 6;
  if ((t & 63) == 0) { rs[w] = s; rq[w] = q; }
  __syncthreads();
  if (t == 0) {
    s = rs[0] + rs[1] + rs[2] + rs[3];
    q = rq[0] + rq[1] + rq[2] + rq[3];
    float mean = s * invN;
    float var = q * invN - mean * mean;
    float rstd = rsqrtf(var + 1e-5f);
    float sc = gamma[m] * rstd;
    scsh[m] = sc;
    scsh[gridDim.x + m] = beta[m] - mean * sc;
  }
}

// ---------------- GEMM2: B (BN1+ReLU) double-buffered LDS, A register-prefetched from global ----
__global__ __launch_bounds__(256) void gemm2_kernel(const u16* __restrict__ W2s, const u16* __restrict__ y1,
                                                    const float* __restrict__ scsh, const float* __restrict__ b2,
                                                    u16* __restrict__ y2, float* __restrict__ ps, float* __restrict__ pq) {
  __shared__ __attribute__((aligned(16))) char lds[32768];
  const int t = threadIdx.x, w = t >> 6, l = t & 63;
  const int wm = w >> 1, wn = w & 1;
  const int nb = blockIdx.x;
  const long n0 = (long)nb * 128;
  const int lm = l & 15, lk = l >> 4, l7 = l & 7;
  v4f acc[4][4];
  #pragma unroll
  for (int i = 0; i < 4; i++)
    #pragma unroll
    for (int j = 0; j < 4; j++) { v4f z = {0.f,0.f,0.f,0.f}; acc[i][j] = z; }
  uint4 breg[4];

  const char* aBase = (const char*)W2s + (long)(wm * 64 + lm) * 128;
  auto loadA = [&](int ks) {
    AF r;
    #pragma unroll
    for (int w32 = 0; w32 < 2; w32++) {
      int off = ((w32 * 4 + lk) ^ l7) << 4;
      #pragma unroll
      for (int mf = 0; mf < 4; mf++)
        r.v[w32][mf] = *(const v8s*)(aBase + mf * 2048 + ks * 16384 + off);
    }
    return r;
  };
  auto loadB = [&](int ks) {
    #pragma unroll
    for (int i = 0; i < 4; i++) {
      int idx = i * 256 + t, n = idx >> 3, blk = idx & 7;
      breg[i] = *(const uint4*)((const char*)y1 + (n0 + n) * 512 + ks * 128 + blk * 16);
    }
  };
  auto writeB = [&](int ks, int buf) {
    #pragma unroll
    for (int i = 0; i < 4; i++) {
      int idx = i * 256 + t, n = idx >> 3, blk = idx & 7;
      const u32* pr = (const u32*)&breg[i];
      u32 outw[4];
      #pragma unroll
      for (int h = 0; h < 4; h++) {
        int k = ks * 64 + blk * 8 + 2 * h;
        u32 x = pr[h];
        float h0 = fmaxf(0.f, scsh[k]     * bf2f(x & 0xffff) + scsh[256 + k]);
        float h1 = fmaxf(0.f, scsh[k + 1] * bf2f(x >> 16)    + scsh[256 + k + 1]);
        outw[h] = (u32)f2bf(h0) | ((u32)f2bf(h1) << 16);
      }
      uint4 v; v.x=outw[0]; v.y=outw[1]; v.z=outw[2]; v.w=outw[3];
      *(uint4*)((char*)lds + buf * 16384 + n * 128 + ((blk ^ (n & 7)) << 4)) = v;
    }
  };

  loadB(0); writeB(0, 0);
  AF aCur = loadA(0);
  __syncthreads();
  #pragma unroll
  for (int ks = 0; ks < 4; ks++) {
    const int buf = ks & 1;
    AF aNxt;
    if (ks < 3) { loadB(ks + 1); aNxt = loadA(ks + 1); }
    const char* Bp = (const char*)lds + buf * 16384;
    #pragma unroll
    for (int w32 = 0; w32 < 2; w32++) {
      int off = ((w32 * 4 + lk) ^ l7) << 4;
      v8s bfr[4];
      #pragma unroll
      for (int nf = 0; nf < 4; nf++)
        bfr[nf] = *(const v8s*)(Bp + (wn * 64 + nf * 16 + lm) * 128 + off);
      #pragma unroll
      for (int mf = 0; mf < 4; mf++)
        #pragma unroll
        for (int nf = 0; nf < 4; nf++)
          acc[mf][nf] = __builtin_amdgcn_mfma_f32_16x16x32_bf16(aCur.v[w32][mf], bfr[nf], acc[mf][nf], 0, 0, 0);
    }
    if (ks < 3) writeB(ks + 1, buf ^ 1);
    __syncthreads();
    if (ks < 3) aCur = aNxt;
  }

  #pragma unroll
  for (int mf = 0; mf < 4; mf++) {
    int m = wm * 64 + mf * 16 + lk * 4;
    float bb0 = b2[m], bb1 = b2[m+1], bb2v = b2[m+2], bb3 = b2[m+3];
    #pragma unroll
    for (int nf = 0; nf < 4; nf++) {
      long n = n0 + wn * 64 + nf * 16 + lm;
      v4f v = acc[mf][nf];
      v[0] += bb0; v[1] += bb1; v[2] += bb2v; v[3] += bb3;
      acc[mf][nf] = v;
      uint2 pk;
      pk.x = (u32)f2bf(v[0]) | ((u32)f2bf(v[1]) << 16);
      pk.y = (u32)f2bf(v[2]) | ((u32)f2bf(v[3]) << 16);
      *(uint2*)((char*)y2 + (n * 128 + m) * 2) = pk;
    }
  }
  #pragma unroll
  for (int mf = 0; mf < 4; mf++) {
    #pragma unroll
    for (int j = 0; j < 4; j++) {
      float s = 0.f, q = 0.f;
      #pragma unroll
      for (int nf = 0; nf < 4; nf++) { float v = acc[mf][nf][j]; s += v; q += v * v; }
      #pragma unroll
      for (int mask = 1; mask <= 8; mask <<= 1) { s += __shfl_xor(s, mask); q += __shfl_xor(q, mask); }
      if (lm == 0) {
        int m = wm * 64 + mf * 16 + lk * 4 + j;
        int col = nb * 2 + wn;
        ps[(long)m * 2048 + col] = s;
        pq[(long)m * 2048 + col] = q;
      }
    }
  }
}

// ---------------- final: out[b][m][p] = relu(bn2(y2)), transpose via LDS ----------------
__global__ __launch_bounds__(256) void final_kernel(const u16* __restrict__ y2, const float* __restrict__ scsh2,
                                                    float* __restrict__ out) {
  __shared__ float tl[64 * 130];
  __shared__ float sc[128], sh[128];
  int b = blockIdx.y, t = threadIdx.x;
  long p0 = (long)blockIdx.x * 64;
  if (t < 128) { sc[t] = scsh2[t]; sh[t] = scsh2[128 + t]; }
  __syncthreads();
  #pragma unroll
  for (int i = 0; i < 4; i++) {
    int idx = i * 256 + t;
    int n = idx >> 4, cb = idx & 15;
    uint4 v = *(const uint4*)((const char*)y2 + (((long)b * NP + p0 + n) * 128 + cb * 8) * 2);
    const u32* pv = (const u32*)&v;
    #pragma unroll
    for (int h = 0; h < 4; h++) {
      int m = cb * 8 + 2 * h;
      u32 x = pv[h];
      tl[n * 130 + m]     = fmaxf(0.f, sc[m]     * bf2f(x & 0xffff) + sh[m]);
      tl[n * 130 + m + 1] = fmaxf(0.f, sc[m + 1] * bf2f(x >> 16)    + sh[m + 1]);
    }
  }
  __syncthreads();
  int m = t & 127, hh = t >> 7;
  float* dst = out + ((long)b * 128 + m) * NP + p0 + hh * 32;
  #pragma unroll
  for (int j = 0; j < 8; j++) {
    int p = hh * 32 + j * 4;
    float4 v;
    v.x = tl[(p + 0) * 130 + m];
    v.y = tl[(p + 1) * 130 + m];
    v.z = tl[(p + 2) * 130 + m];
    v.w = tl[(p + 3) * 130 + m];
    *(float4*)(dst + j * 4) = v;
  }
}

extern "C" void kernel_launch(void* const* d_in, const int* in_sizes, int n_in,
                              void* d_out, int out_size, void* d_ws, size_t ws_size,
                              hipStream_t stream) {
  const float* f1  = (const float*)d_in[0];
  const float* c1  = (const float*)d_in[1];
  const float* f2  = (const float*)d_in[2];
  const float* c2  = (const float*)d_in[3];
  const float* W1  = (const float*)d_in[4];
  const float* b1  = (const float*)d_in[5];
  const float* g1  = (const float*)d_in[6];
  const float* be1 = (const float*)d_in[7];
  const float* W2  = (const float*)d_in[8];
  const float* b2  = (const float*)d_in[9];
  const float* g2  = (const float*)d_in[10];
  const float* be2 = (const float*)d_in[11];
  float* out = (float*)d_out;

  char* ws = (char*)d_ws;
  size_t off = 0;
  auto alloc = [&](size_t sz) { char* p = ws + off; off = (off + sz + 255) & ~(size_t)255; return p; };
  u16*   f2t   = (u16*)  alloc((size_t)BB * NG * D2 * 2);       // 16.8 MB
  u16*   W1s   = (u16*)  alloc(196608);
  u16*   W2s   = (u16*)  alloc(65536);
  float* ps1   = (float*)alloc((size_t)256 * 4096 * 4);         // 4 MB
  float* pq1   = (float*)alloc((size_t)256 * 4096 * 4);         // 4 MB
  float* scsh1 = (float*)alloc(2048);
  float* ps2   = (float*)alloc((size_t)128 * 2048 * 4);
  float* pq2   = (float*)alloc((size_t)128 * 2048 * 4);
  float* scsh2 = (float*)alloc(1024);
  u16*   y1    = (u16*)  alloc((size_t)NPTS * DH * 2);          // 67 MB
  u16*   feat  = (u16*)  alloc((size_t)NPTS * DC * 2);          // 100 MB
  u16*   y2    = (u16*)  feat;  // alias: feat dead once GEMM2 starts

  // knn scratch aliases y1 (y1 only live from gemm1 onward; knn scratch dead by then)
  float* ktD = (float*)y1;                                      // 6.29 MB
  int*   ktI = (int*)((char*)y1 + (size_t)KRANGE * 3 * NPTS * 4 + 256); // 6.29 MB

  hipLaunchKernelGGL(prepw_kernel, dim3(64), dim3(256), 0, stream, W1, W2, W1s, W2s);
  hipLaunchKernelGGL(tf2_kernel, dim3(NG / 64, D2 / 64, BB), dim3(256), 0, stream, f2, f2t);
  hipLaunchKernelGGL(knn_part_kernel, dim3(NP / 256, KRANGE, BB), dim3(256), 0, stream, c1, c2, ktD, ktI, 0);
  hipLaunchKernelGGL(interp_kernel, dim3(NP / 32, BB), dim3(256), 0, stream, f1, f2t, ktD, ktI, feat);
  hipLaunchKernelGGL(gemm1_kernel, dim3(2, NPTS / 128), dim3(512), 0, stream, W1s, feat, b1, y1, ps1, pq1);
  hipLaunchKernelGGL(stats_kernel, dim3(256), dim3(256), 0, stream, ps1, pq1, g1, be1, scsh1, 4096, 1.f / (float)NPTS);
  hipLaunchKernelGGL(gemm2_kernel, dim3(NPTS / 128), dim3(256), 0, stream, W2s, y1, scsh1, b2, y2, ps2, pq2);
  hipLaunchKernelGGL(stats_kernel, dim3(128), dim3(256), 0, stream, ps2, pq2, g2, be2, scsh2, 2048, 1.f / (float)NPTS);
  hipLaunchKernelGGL(final_kernel, dim3(NP / 64, BB), dim3(256), 0, stream, y2, scsh2, out);
}